// Round 8
// baseline (78.749 us; speedup 1.0000x reference)
//
#include <hip/hip_runtime.h>
#include <hip/hip_bf16.h>

constexpr int kNV = 8;
constexpr int kHF = 26;
constexpr int kWF = 88;
constexpr int kC  = 256;
constexpr int kP  = 4;
constexpr int kNU = 33;
constexpr int kNH = 64;
constexpr int kLQ = kNU * kNH;   // 2112

typedef short short8 __attribute__((ext_vector_type(8)));
typedef float floatx4 __attribute__((ext_vector_type(4)));

__device__ __forceinline__ unsigned short f2bf(float x) {
  __hip_bfloat16 h = __float2bfloat16(x);
  unsigned short u;
  __builtin_memcpy(&u, &h, 2);
  return u;
}

// ---------------- setup: geometry + Wcat/bcat + WoutWp + WoutT(bf16), ONE launch --------
// blocks [0, nGeomBlk)      : uv + keep_index
// [nGeomBlk, +128)          : Wcat[256][128] = [Wo | Wa | 0], bcat
// [nGeomBlk+128, +64)       : WoutWp[r] = Wout[r,:].Wp  (4 rows per block)
// [nGeomBlk+192, +256)      : WoutT[c][k] = bf16(Wout[k][c])
__global__ __launch_bounds__(256) void k_setup(
    const float* __restrict__ camk,
    const float* __restrict__ Wout, const float* __restrict__ Wp,
    const float* __restrict__ Wo,   const float* __restrict__ bo,
    const float* __restrict__ Wa,   const float* __restrict__ ba,
    float* __restrict__ uv, float* __restrict__ out_keep,
    float* __restrict__ WoutWp, float* __restrict__ Wcat,
    float* __restrict__ bcat, unsigned short* __restrict__ WoutT,
    int bs, int nGeomBlk) {
  int blk = blockIdx.x;
  int tid = threadIdx.x;
  if (blk < nGeomBlk) {
    int t = blk * 256 + tid;
    if (t >= bs * kLQ) return;
    int b = t / kLQ;
    int ij = t - b * kLQ;
    int i = ij / kNH;
    int j = ij - i * kNH;
    const float* K = camk + b * 9;
    float g0 = (float)(-25.6 + (double)j * (51.2 / 63.0));  //  y
    float g2 = (float)(25.6 - (double)i * 0.8);             // -x
    bool any = false;
    float* dst = uv + (size_t)t * 16;
    for (int k = 0; k < kNV; ++k) {
      float g1 = (float)(4.0 - (double)k * (8.0 / 7.0));    // -z
      float p0 = K[0] * g0 + K[1] * g1 + K[2] * g2;
      float p1 = K[3] * g0 + K[4] * g1 + K[5] * g2;
      float p2 = K[6] * g0 + K[7] * g1 + K[8] * g2;
      float den = (fabsf(p2) < 1e-6f) ? 1e-6f : p2;
      float u = p0 / den / 1408.0f;
      float v = p1 / den / 416.0f;
      any = any || (u >= 0.f && u <= 1.f && v >= 0.f && v <= 1.f);
      dst[k * 2]     = u;
      dst[k * 2 + 1] = v;
    }
    out_keep[t] = any ? 1.f : 0.f;
  } else if (blk < nGeomBlk + 128) {
    int idx = (blk - nGeomBlk) * 256 + tid;   // [0, 32768)
    int k = idx >> 7, c = idx & 127;
    float w = 0.f;
    if (c < 64)      w = Wo[k * 64 + c];
    else if (c < 96) w = Wa[k * 32 + (c - 64)];
    Wcat[idx] = w;
    if (idx < 128) {
      float bb = 0.f;
      if (idx < 64)      bb = bo[idx];
      else if (idx < 96) bb = ba[idx - 64];
      bcat[idx] = bb;
    }
  } else if (blk < nGeomBlk + 192) {
    int r = (blk - nGeomBlk - 128) * 4 + (tid >> 6);
    int lane = tid & 63;
    const float* row = Wout + (size_t)r * kC;
    float s = 0.f;
#pragma unroll
    for (int j = lane; j < kC; j += 64) s += row[j] * Wp[j];
#pragma unroll
    for (int o = 32; o > 0; o >>= 1) s += __shfl_down(s, o, 64);
    if (lane == 0) WoutWp[r] = s;
  } else {
    int c = blk - nGeomBlk - 192;             // column of Wout
    WoutT[(size_t)c * kC + tid] = f2bf(Wout[(size_t)tid * kC + c]);
  }
}

// ---------------- 32x128-tile fp32 GEMM body, K-step 32, float4 loads -------------------
// out = A@B + bias.  Requires K % 32 == 0, N % 128 == 0 (or exactly 128-col problem).
__device__ __forceinline__ void gemm_body(
    const float* __restrict__ A, const float* __restrict__ B,
    const float* __restrict__ bias, float* __restrict__ out,
    int M, int N, int K, int bx, int by) {
  __shared__ float As[32][36];
  __shared__ float Bs[32][128];
  int tid = threadIdx.x;
  int tx = tid & 31, ty = tid >> 5;        // 32 x 8 thread grid
  int row0 = by * 32, col0 = bx * 128;
  int ar = tid >> 3, ak = (tid & 7) * 4;   // A-tile: row, k-quad
  int bc = (tid & 31) * 4, bk = tid >> 5;  // B-tile: col-quad, k-base
  bool arow_ok = (row0 + ar) < M;
  const float* Ap = A + (size_t)(row0 + ar) * K + ak;
  float acc[4][4] = {};
  for (int k0 = 0; k0 < K; k0 += 32) {
    float4 a4 = {0.f, 0.f, 0.f, 0.f};
    if (arow_ok) a4 = *reinterpret_cast<const float4*>(Ap + k0);
    float4 b4[4];
#pragma unroll
    for (int i = 0; i < 4; ++i)
      b4[i] = *reinterpret_cast<const float4*>(
          &B[(size_t)(k0 + bk + 8 * i) * N + col0 + bc]);
    __syncthreads();
    *reinterpret_cast<float4*>(&As[ar][ak]) = a4;
#pragma unroll
    for (int i = 0; i < 4; ++i)
      *reinterpret_cast<float4*>(&Bs[bk + 8 * i][bc]) = b4[i];
    __syncthreads();
#pragma unroll
    for (int kk = 0; kk < 32; ++kk) {
      float4 bv = *reinterpret_cast<const float4*>(&Bs[kk][tx * 4]);
      float av[4];
#pragma unroll
      for (int i = 0; i < 4; ++i) av[i] = As[ty * 4 + i][kk];
#pragma unroll
      for (int i = 0; i < 4; ++i) {
        acc[i][0] += av[i] * bv.x; acc[i][1] += av[i] * bv.y;
        acc[i][2] += av[i] * bv.z; acc[i][3] += av[i] * bv.w;
      }
    }
  }
  int gc = col0 + tx * 4;
  float4 bi = *reinterpret_cast<const float4*>(&bias[gc]);
#pragma unroll
  for (int i = 0; i < 4; ++i) {
    int gr = row0 + ty * 4 + i;
    if (gr >= M) continue;
    float4 r;
    r.x = acc[i][0] + bi.x; r.y = acc[i][1] + bi.y;
    r.z = acc[i][2] + bi.z; r.w = acc[i][3] + bi.w;
    *reinterpret_cast<float4*>(&out[(size_t)gr * N + gc]) = r;
  }
}

// two independent GEMM problems in one dispatch (better CU fill)
__global__ __launch_bounds__(256) void gemm_dual(
    const float* __restrict__ A0, const float* __restrict__ B0,
    const float* __restrict__ bias0, float* __restrict__ out0,
    int M0, int N0, int K0, int yb0,
    const float* __restrict__ A1, const float* __restrict__ B1,
    const float* __restrict__ bias1, float* __restrict__ out1,
    int M1, int N1, int K1, int xb1) {
  if ((int)blockIdx.y < yb0) {
    gemm_body(A0, B0, bias0, out0, M0, N0, K0, blockIdx.x, blockIdx.y);
  } else {
    if ((int)blockIdx.x >= xb1) return;
    gemm_body(A1, B1, bias1, out1, M1, N1, K1, blockIdx.x, blockIdx.y - yb0);
  }
}

// ---------------- bf16 MFMA GEMM: out = Abf@Wout + bias + 2*query ------------------------
// one wave per 16x16 output tile; A[M][256] bf16 bits; BT[c][k] = bf16(Wout[k][c]).
// Fragment maps (m89-verified): A row=lane&15, k=(lane>>4)*8+e; B col=lane&15 same k;
// D col=lane&15, row=(lane>>4)*4+r.
__global__ __launch_bounds__(256) void gemm_mfma(
    const unsigned short* __restrict__ Abf, const unsigned short* __restrict__ BT,
    const float* __restrict__ bias, const float* __restrict__ query,
    float* __restrict__ out, int M) {
  int gw = blockIdx.x * 4 + (threadIdx.x >> 6);
  int lane = threadIdx.x & 63;
  int tr = gw >> 4;                 // M/16 row tiles
  int tc = gw & 15;                 // 256/16 col tiles
  int r0 = tr * 16, c0 = tc * 16;
  if (r0 >= M) return;
  int lrow = lane & 15;
  int kgrp = lane >> 4;
  const unsigned short* Ap = Abf + (size_t)(r0 + lrow) * kC + kgrp * 8;
  const unsigned short* Bp = BT  + (size_t)(c0 + lrow) * kC + kgrp * 8;
  floatx4 acc = {0.f, 0.f, 0.f, 0.f};
#pragma unroll
  for (int k0 = 0; k0 < kC; k0 += 32) {
    short8 a = *reinterpret_cast<const short8*>(Ap + k0);
    short8 b = *reinterpret_cast<const short8*>(Bp + k0);
    acc = __builtin_amdgcn_mfma_f32_16x16x32_bf16(a, b, acc, 0, 0, 0);
  }
  int col = c0 + lrow;
  float bi = bias[col];
#pragma unroll
  for (int r = 0; r < 4; ++r) {
    int row = r0 + kgrp * 4 + r;
    out[(size_t)row * kC + col] =
        acc[r] + bi + 2.0f * query[(size_t)row * kC + col];
  }
}

// ---------------- fused sampling: 2 waves per (b,q), 4 views per wave --------------------
// lane l: head h = l>>3, channels h*32 + (l&7)*4 .. +3 (float4)
__global__ __launch_bounds__(128) void k_fused(
    const float* __restrict__ valp, const float* __restrict__ uv,
    const float* __restrict__ qcat, const float* __restrict__ WoutWp,
    unsigned short* __restrict__ msda_bf, float* __restrict__ out_mhi) {
  int bq = blockIdx.x;
  int b = bq / kLQ;
  int tid = threadIdx.x;
  int wp = tid >> 6;        // wave 0: v=0..3, wave 1: v=4..7
  int lane = tid & 63;
  int h = lane >> 3;
  int dq = lane & 7;
  int ch = h * 32 + dq * 4;

  const float* qp = qcat + (size_t)bq * 128;

  // attention softmax over P for this head
  float4 qa4 = *reinterpret_cast<const float4*>(qp + 64 + h * 4);
  float am = fmaxf(fmaxf(qa4.x, qa4.y), fmaxf(qa4.z, qa4.w));
  float e0 = expf(qa4.x - am), e1 = expf(qa4.y - am);
  float e2 = expf(qa4.z - am), e3 = expf(qa4.w - am);
  float ei = 1.f / (e0 + e1 + e2 + e3);
  float aw[4] = {e0 * ei, e1 * ei, e2 * ei, e3 * ei};

  float4 qo0 = *reinterpret_cast<const float4*>(qp + h * 8);
  float4 qo1 = *reinterpret_cast<const float4*>(qp + h * 8 + 4);
  float offx[4] = {qo0.x, qo0.z, qo1.x, qo1.z};
  float offy[4] = {qo0.y, qo0.w, qo1.y, qo1.w};

  // this wave's 4 view (u,v) pairs
  float ub[4], vb[4];
  const float4* uvp = reinterpret_cast<const float4*>(uv + (size_t)bq * 16) + wp * 2;
#pragma unroll
  for (int i = 0; i < 2; ++i) {
    float4 t = uvp[i];
    ub[2 * i]     = t.x * 88.0f - 0.5f;
    vb[2 * i]     = t.y * 26.0f - 0.5f;
    ub[2 * i + 1] = t.z * 88.0f - 0.5f;
    vb[2 * i + 1] = t.w * 26.0f - 0.5f;
  }

  const float* vp = valp + (size_t)b * (kHF * kWF) * kC + ch;
  float4 w4 = *reinterpret_cast<const float4*>(WoutWp + ch);

  __shared__ float lgs[kNV];
  __shared__ float wks[kNV];
  __shared__ float4 part[64];

  float4 sv[4];
#pragma unroll
  for (int vv = 0; vv < 4; ++vv) {
    float4 s4 = {0.f, 0.f, 0.f, 0.f};
#pragma unroll
    for (int p = 0; p < kP; ++p) {
      float px = ub[vv] + offx[p];
      float py = vb[vv] + offy[p];
      px = fminf(fmaxf(px, -10000.f), 10000.f);
      py = fminf(fmaxf(py, -10000.f), 10000.f);
      float x0f = floorf(px), y0f = floorf(py);
      float lx = px - x0f, ly = py - y0f;
      int x0 = (int)x0f, y0 = (int)y0f;
#pragma unroll
      for (int cy = 0; cy < 2; ++cy) {
#pragma unroll
        for (int cx = 0; cx < 2; ++cx) {
          int xi = x0 + cx, yi = y0 + cy;
          float w = (cx ? lx : 1.f - lx) * (cy ? ly : 1.f - ly) * aw[p];
          bool valid = (xi >= 0) && (xi < kWF) && (yi >= 0) && (yi < kHF);
          int xc = xi < 0 ? 0 : (xi > kWF - 1 ? kWF - 1 : xi);
          int yc = yi < 0 ? 0 : (yi > kHF - 1 ? kHF - 1 : yi);
          float4 g = *reinterpret_cast<const float4*>(vp + (yc * kWF + xc) * kC);
          float wv = valid ? w : 0.f;
          s4.x += wv * g.x; s4.y += wv * g.y; s4.z += wv * g.z; s4.w += wv * g.w;
        }
      }
    }
    sv[vv] = s4;
    float lv = s4.x * w4.x + s4.y * w4.y + s4.z * w4.z + s4.w * w4.w;
#pragma unroll
    for (int o = 32; o > 0; o >>= 1) lv += __shfl_down(lv, o, 64);
    if (lane == 0) lgs[wp * 4 + vv] = lv;
  }
  __syncthreads();
  if (tid == 0) {
    // height softmax + argmax (v-independent constant terms cancel exactly)
    float m = -1e30f; int ai = 0;
#pragma unroll
    for (int v = 0; v < kNV; ++v)
      if (lgs[v] > m) { m = lgs[v]; ai = v; }
    float ssum = 0.f;
    float ev[kNV];
#pragma unroll
    for (int v = 0; v < kNV; ++v) { ev[v] = expf(lgs[v] - m); ssum += ev[v]; }
    float invs = 1.f / ssum;
#pragma unroll
    for (int v = 0; v < kNV; ++v) wks[v] = ev[v] * invs;
    out_mhi[bq] = (float)ai;
  }
  __syncthreads();
  float4 acc = {0.f, 0.f, 0.f, 0.f};
#pragma unroll
  for (int vv = 0; vv < 4; ++vv) {
    float wv = wks[wp * 4 + vv];
    acc.x += wv * sv[vv].x; acc.y += wv * sv[vv].y;
    acc.z += wv * sv[vv].z; acc.w += wv * sv[vv].w;
  }
  if (wp == 1) part[lane] = acc;
  __syncthreads();
  if (wp == 0) {
    float4 pp = part[lane];
    acc.x += pp.x; acc.y += pp.y; acc.z += pp.z; acc.w += pp.w;
    ushort4 pk;
    pk.x = f2bf(acc.x); pk.y = f2bf(acc.y);
    pk.z = f2bf(acc.z); pk.w = f2bf(acc.w);
    *reinterpret_cast<ushort4*>(msda_bf + (size_t)bq * kC + ch) = pk;
  }
}

extern "C" void kernel_launch(void* const* d_in, const int* in_sizes, int n_in,
                              void* d_out, int out_size, void* d_ws, size_t ws_size,
                              hipStream_t stream) {
  if (n_in < 13) return;
  const float* query = (const float*)d_in[0];
  const float* value = (const float*)d_in[1];
  const float* camk  = (const float*)d_in[2];
  const float* Wv    = (const float*)d_in[3];
  const float* bv    = (const float*)d_in[4];
  const float* Wo    = (const float*)d_in[5];
  const float* bo    = (const float*)d_in[6];
  const float* Wa    = (const float*)d_in[7];
  const float* ba    = (const float*)d_in[8];
  const float* Wout  = (const float*)d_in[9];
  const float* bout  = (const float*)d_in[10];
  const float* Wp    = (const float*)d_in[11];
  int bs = in_sizes[0] / (kLQ * kC);
  int MQ = bs * kLQ;          // 4224
  int MV = bs * kHF * kWF;    // 4576

  float* ws = (float*)d_ws;
  size_t o = 0;
  float* valp    = ws + o; o += (size_t)MV * kC;
  float* uv      = ws + o; o += (size_t)MQ * 16;
  float* qcat    = ws + o; o += (size_t)MQ * 128;
  unsigned short* msda_bf = (unsigned short*)(ws + o); o += (size_t)MQ * kC / 2;
  float* WoutWp  = ws + o; o += kC;
  float* Wcat    = ws + o; o += kC * 128;
  float* bcat    = ws + o; o += 128;
  unsigned short* WoutT = (unsigned short*)(ws + o); o += (size_t)kC * kC / 2;
  (void)ws_size; (void)out_size;

  float* outp = (float*)d_out;
  float* out_grd  = outp;                          // bs*LQ*C
  float* out_mhi  = outp + (size_t)MQ * kC;        // bs*LQ
  float* out_keep = out_mhi + (size_t)MQ;          // bs*LQ

  int nGeomBlk = (MQ + 255) / 256;
  k_setup<<<nGeomBlk + 128 + 64 + 256, 256, 0, stream>>>(
      camk, Wout, Wp, Wo, bo, Wa, ba, uv, out_keep, WoutWp, Wcat, bcat, WoutT,
      bs, nGeomBlk);
  int yb0 = (MV + 31) / 32;
  int yb1 = (MQ + 31) / 32;
  gemm_dual<<<dim3(2, yb0 + yb1), 256, 0, stream>>>(
      value, Wv, bv, valp, MV, kC, kC, yb0,
      query, Wcat, bcat, qcat, MQ, 128, kC, 1);
  k_fused<<<MQ, 128, 0, stream>>>(valp, uv, qcat, WoutWp, msda_bf, out_mhi);
  gemm_mfma<<<MQ / 4, 256, 0, stream>>>(msda_bf, WoutT, bout, query, out_grd, MQ);
}

// Round 10
// 68.849 us; speedup vs baseline: 1.1438x; 1.1438x over previous
//
#include <hip/hip_runtime.h>
#include <hip/hip_bf16.h>

constexpr int kNV = 8;
constexpr int kHF = 26;
constexpr int kWF = 88;
constexpr int kC  = 256;
constexpr int kP  = 4;
constexpr int kNU = 33;
constexpr int kNH = 64;
constexpr int kLQ = kNU * kNH;   // 2112

typedef short short8 __attribute__((ext_vector_type(8)));
typedef float floatx4 __attribute__((ext_vector_type(4)));

__device__ __forceinline__ unsigned short f2bf(float x) {
  __hip_bfloat16 h = __float2bfloat16(x);
  unsigned short u;
  __builtin_memcpy(&u, &h, 2);
  return u;
}

// ---------------- setup: geometry + Wcat/bcat + WoutWp + WoutT(bf16), ONE launch --------
// blocks [0, nGeomBlk)      : uv + keep_index
// [nGeomBlk, +128)          : Wcat[256][128] = [Wo | Wa | 0], bcat
// [nGeomBlk+128, +64)       : WoutWp[r] = Wout[r,:].Wp  (4 rows per block)
// [nGeomBlk+192, +256)      : WoutT[c][k] = bf16(Wout[k][c])
__global__ __launch_bounds__(256) void k_setup(
    const float* __restrict__ camk,
    const float* __restrict__ Wout, const float* __restrict__ Wp,
    const float* __restrict__ Wo,   const float* __restrict__ bo,
    const float* __restrict__ Wa,   const float* __restrict__ ba,
    float* __restrict__ uv, float* __restrict__ out_keep,
    float* __restrict__ WoutWp, float* __restrict__ Wcat,
    float* __restrict__ bcat, unsigned short* __restrict__ WoutT,
    int bs, int nGeomBlk) {
  int blk = blockIdx.x;
  int tid = threadIdx.x;
  if (blk < nGeomBlk) {
    int t = blk * 256 + tid;
    if (t >= bs * kLQ) return;
    int b = t / kLQ;
    int ij = t - b * kLQ;
    int i = ij / kNH;
    int j = ij - i * kNH;
    const float* K = camk + b * 9;
    float g0 = (float)(-25.6 + (double)j * (51.2 / 63.0));  //  y
    float g2 = (float)(25.6 - (double)i * 0.8);             // -x
    bool any = false;
    float* dst = uv + (size_t)t * 16;
    for (int k = 0; k < kNV; ++k) {
      float g1 = (float)(4.0 - (double)k * (8.0 / 7.0));    // -z
      float p0 = K[0] * g0 + K[1] * g1 + K[2] * g2;
      float p1 = K[3] * g0 + K[4] * g1 + K[5] * g2;
      float p2 = K[6] * g0 + K[7] * g1 + K[8] * g2;
      float den = (fabsf(p2) < 1e-6f) ? 1e-6f : p2;
      float u = p0 / den / 1408.0f;
      float v = p1 / den / 416.0f;
      any = any || (u >= 0.f && u <= 1.f && v >= 0.f && v <= 1.f);
      dst[k * 2]     = u;
      dst[k * 2 + 1] = v;
    }
    out_keep[t] = any ? 1.f : 0.f;
  } else if (blk < nGeomBlk + 128) {
    int idx = (blk - nGeomBlk) * 256 + tid;   // [0, 32768)
    int k = idx >> 7, c = idx & 127;
    float w = 0.f;
    if (c < 64)      w = Wo[k * 64 + c];
    else if (c < 96) w = Wa[k * 32 + (c - 64)];
    Wcat[idx] = w;
    if (idx < 128) {
      float bb = 0.f;
      if (idx < 64)      bb = bo[idx];
      else if (idx < 96) bb = ba[idx - 64];
      bcat[idx] = bb;
    }
  } else if (blk < nGeomBlk + 192) {
    int r = (blk - nGeomBlk - 128) * 4 + (tid >> 6);
    int lane = tid & 63;
    const float* row = Wout + (size_t)r * kC;
    float s = 0.f;
#pragma unroll
    for (int j = lane; j < kC; j += 64) s += row[j] * Wp[j];
#pragma unroll
    for (int o = 32; o > 0; o >>= 1) s += __shfl_down(s, o, 64);
    if (lane == 0) WoutWp[r] = s;
  } else {
    int c = blk - nGeomBlk - 192;             // column of Wout
    WoutT[(size_t)c * kC + tid] = f2bf(Wout[(size_t)tid * kC + c]);
  }
}

// ---------------- 32x64-tile fp32 GEMM body, K-step 32, float4 loads --------------------
// out = A@B + bias.  Requires K % 32 == 0, N % 64 == 0.
__device__ __forceinline__ void gemm_body(
    const float* __restrict__ A, const float* __restrict__ B,
    const float* __restrict__ bias, float* __restrict__ out,
    int M, int N, int K, int bx, int by) {
  __shared__ float As[32][36];
  __shared__ float Bs[32][64];
  int tid = threadIdx.x;
  int tx = tid & 15, ty = tid >> 4;
  int row0 = by * 32, col0 = bx * 64;
  int ar = tid >> 3, ak = (tid & 7) * 4;   // A-tile: row, k-quad
  int bc = (tid & 15) * 4, bk = tid >> 4;  // B-tile: col-quad, k
  bool arow_ok = (row0 + ar) < M;
  const float* Ap = A + (size_t)(row0 + ar) * K + ak;
  float acc[2][4] = {};
  for (int k0 = 0; k0 < K; k0 += 32) {
    float4 a4 = {0.f, 0.f, 0.f, 0.f};
    if (arow_ok) a4 = *reinterpret_cast<const float4*>(Ap + k0);
    float4 b0 = *reinterpret_cast<const float4*>(&B[(size_t)(k0 + bk) * N + col0 + bc]);
    float4 b1 = *reinterpret_cast<const float4*>(&B[(size_t)(k0 + bk + 16) * N + col0 + bc]);
    __syncthreads();
    *reinterpret_cast<float4*>(&As[ar][ak]) = a4;
    *reinterpret_cast<float4*>(&Bs[bk][bc]) = b0;
    *reinterpret_cast<float4*>(&Bs[bk + 16][bc]) = b1;
    __syncthreads();
#pragma unroll
    for (int kk = 0; kk < 32; ++kk) {
      float a0 = As[ty * 2][kk];
      float a1 = As[ty * 2 + 1][kk];
      float4 b4 = *reinterpret_cast<const float4*>(&Bs[kk][tx * 4]);
      acc[0][0] += a0 * b4.x; acc[0][1] += a0 * b4.y;
      acc[0][2] += a0 * b4.z; acc[0][3] += a0 * b4.w;
      acc[1][0] += a1 * b4.x; acc[1][1] += a1 * b4.y;
      acc[1][2] += a1 * b4.z; acc[1][3] += a1 * b4.w;
    }
  }
  int gc = col0 + tx * 4;
  float4 bi = *reinterpret_cast<const float4*>(&bias[gc]);
#pragma unroll
  for (int i = 0; i < 2; ++i) {
    int gr = row0 + ty * 2 + i;
    if (gr >= M) continue;
    float4 r;
    r.x = acc[i][0] + bi.x; r.y = acc[i][1] + bi.y;
    r.z = acc[i][2] + bi.z; r.w = acc[i][3] + bi.w;
    *reinterpret_cast<float4*>(&out[(size_t)gr * N + gc]) = r;
  }
}

// two independent GEMM problems in one dispatch (better CU fill)
__global__ __launch_bounds__(256) void gemm_dual(
    const float* __restrict__ A0, const float* __restrict__ B0,
    const float* __restrict__ bias0, float* __restrict__ out0,
    int M0, int N0, int K0, int yb0,
    const float* __restrict__ A1, const float* __restrict__ B1,
    const float* __restrict__ bias1, float* __restrict__ out1,
    int M1, int N1, int K1, int xb1) {
  if ((int)blockIdx.y < yb0) {
    gemm_body(A0, B0, bias0, out0, M0, N0, K0, blockIdx.x, blockIdx.y);
  } else {
    if ((int)blockIdx.x >= xb1) return;
    gemm_body(A1, B1, bias1, out1, M1, N1, K1, blockIdx.x, blockIdx.y - yb0);
  }
}

// ---------------- bf16 MFMA GEMM: out = Abf@Wout + bias + 2*query ------------------------
// one wave per 16x16 output tile; A[M][256] bf16 bits; BT[c][k] = bf16(Wout[k][c]).
// Fragment maps (m89-verified): A row=lane&15, k=(lane>>4)*8+e; B col=lane&15 same k;
// D col=lane&15, row=(lane>>4)*4+r.
__global__ __launch_bounds__(256) void gemm_mfma(
    const unsigned short* __restrict__ Abf, const unsigned short* __restrict__ BT,
    const float* __restrict__ bias, const float* __restrict__ query,
    float* __restrict__ out, int M) {
  int gw = blockIdx.x * 4 + (threadIdx.x >> 6);
  int lane = threadIdx.x & 63;
  int tr = gw >> 4;                 // M/16 row tiles
  int tc = gw & 15;                 // 256/16 col tiles
  int r0 = tr * 16, c0 = tc * 16;
  if (r0 >= M) return;
  int lrow = lane & 15;
  int kgrp = lane >> 4;
  const unsigned short* Ap = Abf + (size_t)(r0 + lrow) * kC + kgrp * 8;
  const unsigned short* Bp = BT  + (size_t)(c0 + lrow) * kC + kgrp * 8;
  floatx4 acc = {0.f, 0.f, 0.f, 0.f};
#pragma unroll
  for (int k0 = 0; k0 < kC; k0 += 32) {
    short8 a = *reinterpret_cast<const short8*>(Ap + k0);
    short8 b = *reinterpret_cast<const short8*>(Bp + k0);
    acc = __builtin_amdgcn_mfma_f32_16x16x32_bf16(a, b, acc, 0, 0, 0);
  }
  int col = c0 + lrow;
  float bi = bias[col];
#pragma unroll
  for (int r = 0; r < 4; ++r) {
    int row = r0 + kgrp * 4 + r;
    out[(size_t)row * kC + col] =
        acc[r] + bi + 2.0f * query[(size_t)row * kC + col];
  }
}

// ---------------- fused sampling: 2 waves per (b,q), 4 views per wave --------------------
// lane l: head h = l>>3, channels h*32 + (l&7)*4 .. +3 (float4)
__global__ __launch_bounds__(128) void k_fused(
    const float* __restrict__ valp, const float* __restrict__ uv,
    const float* __restrict__ qcat, const float* __restrict__ WoutWp,
    unsigned short* __restrict__ msda_bf, float* __restrict__ out_mhi) {
  int bq = blockIdx.x;
  int b = bq / kLQ;
  int tid = threadIdx.x;
  int wp = tid >> 6;        // wave 0: v=0..3, wave 1: v=4..7
  int lane = tid & 63;
  int h = lane >> 3;
  int dq = lane & 7;
  int ch = h * 32 + dq * 4;

  const float* qp = qcat + (size_t)bq * 128;

  // attention softmax over P for this head
  float4 qa4 = *reinterpret_cast<const float4*>(qp + 64 + h * 4);
  float am = fmaxf(fmaxf(qa4.x, qa4.y), fmaxf(qa4.z, qa4.w));
  float e0 = expf(qa4.x - am), e1 = expf(qa4.y - am);
  float e2 = expf(qa4.z - am), e3 = expf(qa4.w - am);
  float ei = 1.f / (e0 + e1 + e2 + e3);
  float aw[4] = {e0 * ei, e1 * ei, e2 * ei, e3 * ei};

  float4 qo0 = *reinterpret_cast<const float4*>(qp + h * 8);
  float4 qo1 = *reinterpret_cast<const float4*>(qp + h * 8 + 4);
  float offx[4] = {qo0.x, qo0.z, qo1.x, qo1.z};
  float offy[4] = {qo0.y, qo0.w, qo1.y, qo1.w};

  // this wave's 4 view (u,v) pairs
  float ub[4], vb[4];
  const float4* uvp = reinterpret_cast<const float4*>(uv + (size_t)bq * 16) + wp * 2;
#pragma unroll
  for (int i = 0; i < 2; ++i) {
    float4 t = uvp[i];
    ub[2 * i]     = t.x * 88.0f - 0.5f;
    vb[2 * i]     = t.y * 26.0f - 0.5f;
    ub[2 * i + 1] = t.z * 88.0f - 0.5f;
    vb[2 * i + 1] = t.w * 26.0f - 0.5f;
  }

  const float* vp = valp + (size_t)b * (kHF * kWF) * kC + ch;
  float4 w4 = *reinterpret_cast<const float4*>(WoutWp + ch);

  __shared__ float lgs[kNV];
  __shared__ float wks[kNV];
  __shared__ float4 part[64];

  float4 sv[4];
#pragma unroll
  for (int vv = 0; vv < 4; ++vv) {
    float4 s4 = {0.f, 0.f, 0.f, 0.f};
#pragma unroll
    for (int p = 0; p < kP; ++p) {
      float px = ub[vv] + offx[p];
      float py = vb[vv] + offy[p];
      px = fminf(fmaxf(px, -10000.f), 10000.f);
      py = fminf(fmaxf(py, -10000.f), 10000.f);
      float x0f = floorf(px), y0f = floorf(py);
      float lx = px - x0f, ly = py - y0f;
      int x0 = (int)x0f, y0 = (int)y0f;
#pragma unroll
      for (int cy = 0; cy < 2; ++cy) {
#pragma unroll
        for (int cx = 0; cx < 2; ++cx) {
          int xi = x0 + cx, yi = y0 + cy;
          float w = (cx ? lx : 1.f - lx) * (cy ? ly : 1.f - ly) * aw[p];
          bool valid = (xi >= 0) && (xi < kWF) && (yi >= 0) && (yi < kHF);
          int xc = xi < 0 ? 0 : (xi > kWF - 1 ? kWF - 1 : xi);
          int yc = yi < 0 ? 0 : (yi > kHF - 1 ? kHF - 1 : yi);
          float4 g = *reinterpret_cast<const float4*>(vp + (yc * kWF + xc) * kC);
          float wv = valid ? w : 0.f;
          s4.x += wv * g.x; s4.y += wv * g.y; s4.z += wv * g.z; s4.w += wv * g.w;
        }
      }
    }
    sv[vv] = s4;
    float lv = s4.x * w4.x + s4.y * w4.y + s4.z * w4.z + s4.w * w4.w;
#pragma unroll
    for (int o = 32; o > 0; o >>= 1) lv += __shfl_down(lv, o, 64);
    if (lane == 0) lgs[wp * 4 + vv] = lv;
  }
  __syncthreads();
  if (tid == 0) {
    // height softmax + argmax (v-independent constant terms cancel exactly)
    float m = -1e30f; int ai = 0;
#pragma unroll
    for (int v = 0; v < kNV; ++v)
      if (lgs[v] > m) { m = lgs[v]; ai = v; }
    float ssum = 0.f;
    float ev[kNV];
#pragma unroll
    for (int v = 0; v < kNV; ++v) { ev[v] = expf(lgs[v] - m); ssum += ev[v]; }
    float invs = 1.f / ssum;
#pragma unroll
    for (int v = 0; v < kNV; ++v) wks[v] = ev[v] * invs;
    out_mhi[bq] = (float)ai;
  }
  __syncthreads();
  float4 acc = {0.f, 0.f, 0.f, 0.f};
#pragma unroll
  for (int vv = 0; vv < 4; ++vv) {
    float wv = wks[wp * 4 + vv];
    acc.x += wv * sv[vv].x; acc.y += wv * sv[vv].y;
    acc.z += wv * sv[vv].z; acc.w += wv * sv[vv].w;
  }
  if (wp == 1) part[lane] = acc;
  __syncthreads();
  if (wp == 0) {
    float4 pp = part[lane];
    acc.x += pp.x; acc.y += pp.y; acc.z += pp.z; acc.w += pp.w;
    ushort4 pk;
    pk.x = f2bf(acc.x); pk.y = f2bf(acc.y);
    pk.z = f2bf(acc.z); pk.w = f2bf(acc.w);
    *reinterpret_cast<ushort4*>(msda_bf + (size_t)bq * kC + ch) = pk;
  }
}

extern "C" void kernel_launch(void* const* d_in, const int* in_sizes, int n_in,
                              void* d_out, int out_size, void* d_ws, size_t ws_size,
                              hipStream_t stream) {
  if (n_in < 13) return;
  const float* query = (const float*)d_in[0];
  const float* value = (const float*)d_in[1];
  const float* camk  = (const float*)d_in[2];
  const float* Wv    = (const float*)d_in[3];
  const float* bv    = (const float*)d_in[4];
  const float* Wo    = (const float*)d_in[5];
  const float* bo    = (const float*)d_in[6];
  const float* Wa    = (const float*)d_in[7];
  const float* ba    = (const float*)d_in[8];
  const float* Wout  = (const float*)d_in[9];
  const float* bout  = (const float*)d_in[10];
  const float* Wp    = (const float*)d_in[11];
  int bs = in_sizes[0] / (kLQ * kC);
  int MQ = bs * kLQ;          // 4224
  int MV = bs * kHF * kWF;    // 4576

  float* ws = (float*)d_ws;
  size_t o = 0;
  float* valp    = ws + o; o += (size_t)MV * kC;
  float* uv      = ws + o; o += (size_t)MQ * 16;
  float* qcat    = ws + o; o += (size_t)MQ * 128;
  unsigned short* msda_bf = (unsigned short*)(ws + o); o += (size_t)MQ * kC / 2;
  float* WoutWp  = ws + o; o += kC;
  float* Wcat    = ws + o; o += kC * 128;
  float* bcat    = ws + o; o += 128;
  unsigned short* WoutT = (unsigned short*)(ws + o); o += (size_t)kC * kC / 2;
  (void)ws_size; (void)out_size;

  float* outp = (float*)d_out;
  float* out_grd  = outp;                          // bs*LQ*C
  float* out_mhi  = outp + (size_t)MQ * kC;        // bs*LQ
  float* out_keep = out_mhi + (size_t)MQ;          // bs*LQ

  int nGeomBlk = (MQ + 255) / 256;
  k_setup<<<nGeomBlk + 128 + 64 + 256, 256, 0, stream>>>(
      camk, Wout, Wp, Wo, bo, Wa, ba, uv, out_keep, WoutWp, Wcat, bcat, WoutT,
      bs, nGeomBlk);
  int yb0 = (MV + 31) / 32;
  int yb1 = (MQ + 31) / 32;
  gemm_dual<<<dim3(4, yb0 + yb1), 256, 0, stream>>>(
      value, Wv, bv, valp, MV, kC, kC, yb0,
      query, Wcat, bcat, qcat, MQ, 128, kC, 2);
  k_fused<<<MQ, 128, 0, stream>>>(valp, uv, qcat, WoutWp, msda_bf, out_mhi);
  gemm_mfma<<<MQ / 4, 256, 0, stream>>>(msda_bf, WoutT, bout, query, out_grd, MQ);
}

// Round 11
// 58.596 us; speedup vs baseline: 1.3439x; 1.1750x over previous
//
#include <hip/hip_runtime.h>
#include <hip/hip_bf16.h>

constexpr int kNV = 8;
constexpr int kHF = 26;
constexpr int kWF = 88;
constexpr int kC  = 256;
constexpr int kP  = 4;
constexpr int kNU = 33;
constexpr int kNH = 64;
constexpr int kLQ = kNU * kNH;   // 2112

typedef short short8 __attribute__((ext_vector_type(8)));
typedef float floatx4 __attribute__((ext_vector_type(4)));

__device__ __forceinline__ unsigned short f2bf(float x) {
  __hip_bfloat16 h = __float2bfloat16(x);
  unsigned short u;
  __builtin_memcpy(&u, &h, 2);
  return u;
}

// ---------------- 32x64-tile fp32 GEMM body, K-step 32, float4 loads --------------------
// VIRT=false: B/bias are real arrays. VIRT=true: B = [Wo | Wa | 0] concat (N=128),
// bias = [bo | ba | 0]. Requires K % 32 == 0, N % 64 == 0; col regions 4-aligned.
template <bool VIRT>
__device__ __forceinline__ void gemm_body(
    const float* __restrict__ A, const float* __restrict__ B,
    const float* __restrict__ bias,
    const float* __restrict__ Wo, const float* __restrict__ Wa,
    const float* __restrict__ bo, const float* __restrict__ ba,
    float* __restrict__ out, int M, int N, int K, int bx, int by) {
  __shared__ float As[32][36];
  __shared__ float Bs[32][64];
  int tid = threadIdx.x;
  int tx = tid & 15, ty = tid >> 4;
  int row0 = by * 32, col0 = bx * 64;
  int ar = tid >> 3, ak = (tid & 7) * 4;   // A-tile: row, k-quad
  int bc = (tid & 15) * 4, bk = tid >> 4;  // B-tile: col-quad, k
  bool arow_ok = (row0 + ar) < M;
  const float* Ap = A + (size_t)(row0 + ar) * K + ak;
  int cb = col0 + bc;
  float acc[2][4] = {};
  for (int k0 = 0; k0 < K; k0 += 32) {
    float4 a4 = {0.f, 0.f, 0.f, 0.f};
    if (arow_ok) a4 = *reinterpret_cast<const float4*>(Ap + k0);
    float4 b0, b1;
    if (!VIRT) {
      b0 = *reinterpret_cast<const float4*>(&B[(size_t)(k0 + bk) * N + cb]);
      b1 = *reinterpret_cast<const float4*>(&B[(size_t)(k0 + bk + 16) * N + cb]);
    } else {
      if (cb < 64) {
        b0 = *reinterpret_cast<const float4*>(&Wo[(k0 + bk) * 64 + cb]);
        b1 = *reinterpret_cast<const float4*>(&Wo[(k0 + bk + 16) * 64 + cb]);
      } else if (cb < 96) {
        b0 = *reinterpret_cast<const float4*>(&Wa[(k0 + bk) * 32 + cb - 64]);
        b1 = *reinterpret_cast<const float4*>(&Wa[(k0 + bk + 16) * 32 + cb - 64]);
      } else {
        b0 = float4{0.f, 0.f, 0.f, 0.f};
        b1 = float4{0.f, 0.f, 0.f, 0.f};
      }
    }
    __syncthreads();
    *reinterpret_cast<float4*>(&As[ar][ak]) = a4;
    *reinterpret_cast<float4*>(&Bs[bk][bc]) = b0;
    *reinterpret_cast<float4*>(&Bs[bk + 16][bc]) = b1;
    __syncthreads();
#pragma unroll
    for (int kk = 0; kk < 32; ++kk) {
      float a0 = As[ty * 2][kk];
      float a1 = As[ty * 2 + 1][kk];
      float4 b4 = *reinterpret_cast<const float4*>(&Bs[kk][tx * 4]);
      acc[0][0] += a0 * b4.x; acc[0][1] += a0 * b4.y;
      acc[0][2] += a0 * b4.z; acc[0][3] += a0 * b4.w;
      acc[1][0] += a1 * b4.x; acc[1][1] += a1 * b4.y;
      acc[1][2] += a1 * b4.z; acc[1][3] += a1 * b4.w;
    }
  }
  int gc = col0 + tx * 4;
  float4 bi;
  if (!VIRT) {
    bi = *reinterpret_cast<const float4*>(&bias[gc]);
  } else if (gc < 64) {
    bi = *reinterpret_cast<const float4*>(&bo[gc]);
  } else if (gc < 96) {
    bi = *reinterpret_cast<const float4*>(&ba[gc - 64]);
  } else {
    bi = float4{0.f, 0.f, 0.f, 0.f};
  }
#pragma unroll
  for (int i = 0; i < 2; ++i) {
    int gr = row0 + ty * 2 + i;
    if (gr >= M) continue;
    float4 r;
    r.x = acc[i][0] + bi.x; r.y = acc[i][1] + bi.y;
    r.z = acc[i][2] + bi.z; r.w = acc[i][3] + bi.w;
    *reinterpret_cast<float4*>(&out[(size_t)gr * N + gc]) = r;
  }
}

// ---------------- front: valp GEMM + qcat GEMM(virtual B) + geom + WoutWp + WoutT -------
// blocks [0, nValp)            : valp = value@Wv + bv          (bx=blk&3, by=blk>>2)
// [nValp, +nQ)                 : qcat = query@[Wo|Wa|0] + bias (bx=r&1,  by=r>>1)
// [nValp+nQ, +nGeomBlk)        : uv + keep_index
// [.., +64)                    : WoutWp[r] = Wout[r,:].Wp  (4 rows per block)
// [.., +256)                   : WoutT[c][k] = bf16(Wout[k][c])
__global__ __launch_bounds__(256) void k_front(
    const float* __restrict__ value, const float* __restrict__ Wv,
    const float* __restrict__ bv, float* __restrict__ valp,
    const float* __restrict__ query, float* __restrict__ qcat,
    const float* __restrict__ Wo, const float* __restrict__ Wa,
    const float* __restrict__ bo, const float* __restrict__ ba,
    const float* __restrict__ camk, float* __restrict__ uv,
    float* __restrict__ out_keep,
    const float* __restrict__ Wout, const float* __restrict__ Wp,
    float* __restrict__ WoutWp, unsigned short* __restrict__ WoutT,
    int bs, int MV, int MQ, int nValp, int nQ, int nGeomBlk) {
  int blk = blockIdx.x;
  int tid = threadIdx.x;
  if (blk < nValp) {
    gemm_body<false>(value, Wv, bv, nullptr, nullptr, nullptr, nullptr,
                     valp, MV, kC, kC, blk & 3, blk >> 2);
  } else if (blk < nValp + nQ) {
    int r = blk - nValp;
    gemm_body<true>(query, nullptr, nullptr, Wo, Wa, bo, ba,
                    qcat, MQ, 128, kC, r & 1, r >> 1);
  } else if (blk < nValp + nQ + nGeomBlk) {
    int t = (blk - nValp - nQ) * 256 + tid;
    if (t >= bs * kLQ) return;
    int b = t / kLQ;
    int ij = t - b * kLQ;
    int i = ij / kNH;
    int j = ij - i * kNH;
    const float* K = camk + b * 9;
    float g0 = (float)(-25.6 + (double)j * (51.2 / 63.0));  //  y
    float g2 = (float)(25.6 - (double)i * 0.8);             // -x
    bool any = false;
    float* dst = uv + (size_t)t * 16;
    for (int k = 0; k < kNV; ++k) {
      float g1 = (float)(4.0 - (double)k * (8.0 / 7.0));    // -z
      float p0 = K[0] * g0 + K[1] * g1 + K[2] * g2;
      float p1 = K[3] * g0 + K[4] * g1 + K[5] * g2;
      float p2 = K[6] * g0 + K[7] * g1 + K[8] * g2;
      float den = (fabsf(p2) < 1e-6f) ? 1e-6f : p2;
      float u = p0 / den / 1408.0f;
      float v = p1 / den / 416.0f;
      any = any || (u >= 0.f && u <= 1.f && v >= 0.f && v <= 1.f);
      dst[k * 2]     = u;
      dst[k * 2 + 1] = v;
    }
    out_keep[t] = any ? 1.f : 0.f;
  } else if (blk < nValp + nQ + nGeomBlk + 64) {
    int r = (blk - nValp - nQ - nGeomBlk) * 4 + (tid >> 6);
    int lane = tid & 63;
    const float* row = Wout + (size_t)r * kC;
    float s = 0.f;
#pragma unroll
    for (int j = lane; j < kC; j += 64) s += row[j] * Wp[j];
#pragma unroll
    for (int o = 32; o > 0; o >>= 1) s += __shfl_down(s, o, 64);
    if (lane == 0) WoutWp[r] = s;
  } else {
    int c = blk - nValp - nQ - nGeomBlk - 64;   // column of Wout
    WoutT[(size_t)c * kC + tid] = f2bf(Wout[(size_t)tid * kC + c]);
  }
}

// ---------------- bf16 MFMA GEMM: out = Abf@Wout + bias + 2*query ------------------------
__global__ __launch_bounds__(256) void gemm_mfma(
    const unsigned short* __restrict__ Abf, const unsigned short* __restrict__ BT,
    const float* __restrict__ bias, const float* __restrict__ query,
    float* __restrict__ out, int M) {
  int gw = blockIdx.x * 4 + (threadIdx.x >> 6);
  int lane = threadIdx.x & 63;
  int tr = gw >> 4;                 // M/16 row tiles
  int tc = gw & 15;                 // 256/16 col tiles
  int r0 = tr * 16, c0 = tc * 16;
  if (r0 >= M) return;
  int lrow = lane & 15;
  int kgrp = lane >> 4;
  const unsigned short* Ap = Abf + (size_t)(r0 + lrow) * kC + kgrp * 8;
  const unsigned short* Bp = BT  + (size_t)(c0 + lrow) * kC + kgrp * 8;
  floatx4 acc = {0.f, 0.f, 0.f, 0.f};
#pragma unroll
  for (int k0 = 0; k0 < kC; k0 += 32) {
    short8 a = *reinterpret_cast<const short8*>(Ap + k0);
    short8 b = *reinterpret_cast<const short8*>(Bp + k0);
    acc = __builtin_amdgcn_mfma_f32_16x16x32_bf16(a, b, acc, 0, 0, 0);
  }
  int col = c0 + lrow;
  float bi = bias[col];
#pragma unroll
  for (int r = 0; r < 4; ++r) {
    int row = r0 + kgrp * 4 + r;
    out[(size_t)row * kC + col] =
        acc[r] + bi + 2.0f * query[(size_t)row * kC + col];
  }
}

// ---------------- fused sampling: 4 waves per (b,q), 2 views per wave --------------------
// lane l: head h = l>>3, channels h*32 + (l&7)*4 .. +3 (float4)
__global__ __launch_bounds__(256) void k_fused(
    const float* __restrict__ valp, const float* __restrict__ uv,
    const float* __restrict__ qcat, const float* __restrict__ WoutWp,
    unsigned short* __restrict__ msda_bf, float* __restrict__ out_mhi) {
  int bq = blockIdx.x;
  int b = bq / kLQ;
  int tid = threadIdx.x;
  int wp = tid >> 6;        // wave w handles views 2w, 2w+1
  int lane = tid & 63;
  int h = lane >> 3;
  int dq = lane & 7;
  int ch = h * 32 + dq * 4;

  const float* qp = qcat + (size_t)bq * 128;

  // attention softmax over P for this head
  float4 qa4 = *reinterpret_cast<const float4*>(qp + 64 + h * 4);
  float am = fmaxf(fmaxf(qa4.x, qa4.y), fmaxf(qa4.z, qa4.w));
  float e0 = expf(qa4.x - am), e1 = expf(qa4.y - am);
  float e2 = expf(qa4.z - am), e3 = expf(qa4.w - am);
  float ei = 1.f / (e0 + e1 + e2 + e3);
  float aw[4] = {e0 * ei, e1 * ei, e2 * ei, e3 * ei};

  float4 qo0 = *reinterpret_cast<const float4*>(qp + h * 8);
  float4 qo1 = *reinterpret_cast<const float4*>(qp + h * 8 + 4);
  float offx[4] = {qo0.x, qo0.z, qo1.x, qo1.z};
  float offy[4] = {qo0.y, qo0.w, qo1.y, qo1.w};

  // this wave's 2 view (u,v) pairs
  float4 t4 = reinterpret_cast<const float4*>(uv + (size_t)bq * 16)[wp];
  float ub[2], vb[2];
  ub[0] = t4.x * 88.0f - 0.5f;
  vb[0] = t4.y * 26.0f - 0.5f;
  ub[1] = t4.z * 88.0f - 0.5f;
  vb[1] = t4.w * 26.0f - 0.5f;

  const float* vp = valp + (size_t)b * (kHF * kWF) * kC + ch;
  float4 w4 = *reinterpret_cast<const float4*>(WoutWp + ch);

  __shared__ float lgs[kNV];
  __shared__ float wks[kNV];
  __shared__ float4 part[3][64];

  float4 sv[2];
#pragma unroll
  for (int vv = 0; vv < 2; ++vv) {
    float4 s4 = {0.f, 0.f, 0.f, 0.f};
#pragma unroll
    for (int p = 0; p < kP; ++p) {
      float px = ub[vv] + offx[p];
      float py = vb[vv] + offy[p];
      px = fminf(fmaxf(px, -10000.f), 10000.f);
      py = fminf(fmaxf(py, -10000.f), 10000.f);
      float x0f = floorf(px), y0f = floorf(py);
      float lx = px - x0f, ly = py - y0f;
      int x0 = (int)x0f, y0 = (int)y0f;
#pragma unroll
      for (int cy = 0; cy < 2; ++cy) {
#pragma unroll
        for (int cx = 0; cx < 2; ++cx) {
          int xi = x0 + cx, yi = y0 + cy;
          float w = (cx ? lx : 1.f - lx) * (cy ? ly : 1.f - ly) * aw[p];
          bool valid = (xi >= 0) && (xi < kWF) && (yi >= 0) && (yi < kHF);
          int xc = xi < 0 ? 0 : (xi > kWF - 1 ? kWF - 1 : xi);
          int yc = yi < 0 ? 0 : (yi > kHF - 1 ? kHF - 1 : yi);
          float4 g = *reinterpret_cast<const float4*>(vp + (yc * kWF + xc) * kC);
          float wv = valid ? w : 0.f;
          s4.x += wv * g.x; s4.y += wv * g.y; s4.z += wv * g.z; s4.w += wv * g.w;
        }
      }
    }
    sv[vv] = s4;
    float lv = s4.x * w4.x + s4.y * w4.y + s4.z * w4.z + s4.w * w4.w;
#pragma unroll
    for (int o = 32; o > 0; o >>= 1) lv += __shfl_down(lv, o, 64);
    if (lane == 0) lgs[wp * 2 + vv] = lv;
  }
  __syncthreads();
  if (tid == 0) {
    // height softmax + argmax (v-independent constant terms cancel exactly)
    float m = -1e30f; int ai = 0;
#pragma unroll
    for (int v = 0; v < kNV; ++v)
      if (lgs[v] > m) { m = lgs[v]; ai = v; }
    float ssum = 0.f;
    float ev[kNV];
#pragma unroll
    for (int v = 0; v < kNV; ++v) { ev[v] = expf(lgs[v] - m); ssum += ev[v]; }
    float invs = 1.f / ssum;
#pragma unroll
    for (int v = 0; v < kNV; ++v) wks[v] = ev[v] * invs;
    out_mhi[bq] = (float)ai;
  }
  __syncthreads();
  float4 acc = {0.f, 0.f, 0.f, 0.f};
#pragma unroll
  for (int vv = 0; vv < 2; ++vv) {
    float wv = wks[wp * 2 + vv];
    acc.x += wv * sv[vv].x; acc.y += wv * sv[vv].y;
    acc.z += wv * sv[vv].z; acc.w += wv * sv[vv].w;
  }
  if (wp > 0) part[wp - 1][lane] = acc;
  __syncthreads();
  if (wp == 0) {
#pragma unroll
    for (int i = 0; i < 3; ++i) {
      float4 pp = part[i][lane];
      acc.x += pp.x; acc.y += pp.y; acc.z += pp.z; acc.w += pp.w;
    }
    ushort4 pk;
    pk.x = f2bf(acc.x); pk.y = f2bf(acc.y);
    pk.z = f2bf(acc.z); pk.w = f2bf(acc.w);
    *reinterpret_cast<ushort4*>(msda_bf + (size_t)bq * kC + ch) = pk;
  }
}

extern "C" void kernel_launch(void* const* d_in, const int* in_sizes, int n_in,
                              void* d_out, int out_size, void* d_ws, size_t ws_size,
                              hipStream_t stream) {
  if (n_in < 13) return;
  const float* query = (const float*)d_in[0];
  const float* value = (const float*)d_in[1];
  const float* camk  = (const float*)d_in[2];
  const float* Wv    = (const float*)d_in[3];
  const float* bv    = (const float*)d_in[4];
  const float* Wo    = (const float*)d_in[5];
  const float* bo    = (const float*)d_in[6];
  const float* Wa    = (const float*)d_in[7];
  const float* ba    = (const float*)d_in[8];
  const float* Wout  = (const float*)d_in[9];
  const float* bout  = (const float*)d_in[10];
  const float* Wp    = (const float*)d_in[11];
  int bs = in_sizes[0] / (kLQ * kC);
  int MQ = bs * kLQ;          // 4224
  int MV = bs * kHF * kWF;    // 4576

  float* ws = (float*)d_ws;
  size_t o = 0;
  float* valp    = ws + o; o += (size_t)MV * kC;
  float* uv      = ws + o; o += (size_t)MQ * 16;
  float* qcat    = ws + o; o += (size_t)MQ * 128;
  unsigned short* msda_bf = (unsigned short*)(ws + o); o += (size_t)MQ * kC / 2;
  float* WoutWp  = ws + o; o += kC;
  unsigned short* WoutT = (unsigned short*)(ws + o); o += (size_t)kC * kC / 2;
  (void)ws_size; (void)out_size;

  float* outp = (float*)d_out;
  float* out_grd  = outp;                          // bs*LQ*C
  float* out_mhi  = outp + (size_t)MQ * kC;        // bs*LQ
  float* out_keep = out_mhi + (size_t)MQ;          // bs*LQ

  int nGeomBlk = (MQ + 255) / 256;
  int yb0 = (MV + 31) / 32;
  int yb1 = (MQ + 31) / 32;
  int nValp = 4 * yb0;
  int nQ = 2 * yb1;
  k_front<<<nValp + nQ + nGeomBlk + 64 + 256, 256, 0, stream>>>(
      value, Wv, bv, valp, query, qcat, Wo, Wa, bo, ba,
      camk, uv, out_keep, Wout, Wp, WoutWp, WoutT,
      bs, MV, MQ, nValp, nQ, nGeomBlk);
  k_fused<<<MQ, 256, 0, stream>>>(valp, uv, qcat, WoutWp, msda_bf, out_mhi);
  gemm_mfma<<<MQ / 4, 256, 0, stream>>>(msda_bf, WoutT, bout, query, out_grd, MQ);
}

// Round 12
// 53.462 us; speedup vs baseline: 1.4730x; 1.0960x over previous
//
#include <hip/hip_runtime.h>
#include <hip/hip_bf16.h>

constexpr int kNV = 8;
constexpr int kHF = 26;
constexpr int kWF = 88;
constexpr int kC  = 256;
constexpr int kP  = 4;
constexpr int kNU = 33;
constexpr int kNH = 64;
constexpr int kLQ = kNU * kNH;   // 2112

typedef short short8 __attribute__((ext_vector_type(8)));
typedef float floatx4 __attribute__((ext_vector_type(4)));

__device__ __forceinline__ unsigned short f2bf(float x) {
  __hip_bfloat16 h = __float2bfloat16(x);
  unsigned short u;
  __builtin_memcpy(&u, &h, 2);
  return u;
}

// ---------------- 32x64-tile fp32 GEMM body, K-step 32, float4 loads --------------------
// VIRT=false: B/bias are real arrays. VIRT=true: B = [Wo | Wa | 0] concat (N=128),
// bias = [bo | ba | 0]. Requires K % 32 == 0, N % 64 == 0; col regions 4-aligned.
template <bool VIRT>
__device__ __forceinline__ void gemm_body(
    const float* __restrict__ A, const float* __restrict__ B,
    const float* __restrict__ bias,
    const float* __restrict__ Wo, const float* __restrict__ Wa,
    const float* __restrict__ bo, const float* __restrict__ ba,
    float* __restrict__ out, int M, int N, int K, int bx, int by) {
  __shared__ float As[32][36];
  __shared__ float Bs[32][64];
  int tid = threadIdx.x;
  int tx = tid & 15, ty = tid >> 4;
  int row0 = by * 32, col0 = bx * 64;
  int ar = tid >> 3, ak = (tid & 7) * 4;   // A-tile: row, k-quad
  int bc = (tid & 15) * 4, bk = tid >> 4;  // B-tile: col-quad, k
  bool arow_ok = (row0 + ar) < M;
  const float* Ap = A + (size_t)(row0 + ar) * K + ak;
  int cb = col0 + bc;
  float acc[2][4] = {};
  for (int k0 = 0; k0 < K; k0 += 32) {
    float4 a4 = {0.f, 0.f, 0.f, 0.f};
    if (arow_ok) a4 = *reinterpret_cast<const float4*>(Ap + k0);
    float4 b0, b1;
    if (!VIRT) {
      b0 = *reinterpret_cast<const float4*>(&B[(size_t)(k0 + bk) * N + cb]);
      b1 = *reinterpret_cast<const float4*>(&B[(size_t)(k0 + bk + 16) * N + cb]);
    } else {
      if (cb < 64) {
        b0 = *reinterpret_cast<const float4*>(&Wo[(k0 + bk) * 64 + cb]);
        b1 = *reinterpret_cast<const float4*>(&Wo[(k0 + bk + 16) * 64 + cb]);
      } else if (cb < 96) {
        b0 = *reinterpret_cast<const float4*>(&Wa[(k0 + bk) * 32 + cb - 64]);
        b1 = *reinterpret_cast<const float4*>(&Wa[(k0 + bk + 16) * 32 + cb - 64]);
      } else {
        b0 = float4{0.f, 0.f, 0.f, 0.f};
        b1 = float4{0.f, 0.f, 0.f, 0.f};
      }
    }
    __syncthreads();
    *reinterpret_cast<float4*>(&As[ar][ak]) = a4;
    *reinterpret_cast<float4*>(&Bs[bk][bc]) = b0;
    *reinterpret_cast<float4*>(&Bs[bk + 16][bc]) = b1;
    __syncthreads();
#pragma unroll
    for (int kk = 0; kk < 32; ++kk) {
      float a0 = As[ty * 2][kk];
      float a1 = As[ty * 2 + 1][kk];
      float4 b4 = *reinterpret_cast<const float4*>(&Bs[kk][tx * 4]);
      acc[0][0] += a0 * b4.x; acc[0][1] += a0 * b4.y;
      acc[0][2] += a0 * b4.z; acc[0][3] += a0 * b4.w;
      acc[1][0] += a1 * b4.x; acc[1][1] += a1 * b4.y;
      acc[1][2] += a1 * b4.z; acc[1][3] += a1 * b4.w;
    }
  }
  int gc = col0 + tx * 4;
  float4 bi;
  if (!VIRT) {
    bi = *reinterpret_cast<const float4*>(&bias[gc]);
  } else if (gc < 64) {
    bi = *reinterpret_cast<const float4*>(&bo[gc]);
  } else if (gc < 96) {
    bi = *reinterpret_cast<const float4*>(&ba[gc - 64]);
  } else {
    bi = float4{0.f, 0.f, 0.f, 0.f};
  }
#pragma unroll
  for (int i = 0; i < 2; ++i) {
    int gr = row0 + ty * 2 + i;
    if (gr >= M) continue;
    float4 r;
    r.x = acc[i][0] + bi.x; r.y = acc[i][1] + bi.y;
    r.z = acc[i][2] + bi.z; r.w = acc[i][3] + bi.w;
    *reinterpret_cast<float4*>(&out[(size_t)gr * N + gc]) = r;
  }
}

// ---------------- front: valp GEMM + qcat GEMM(virtual B) + geom + WoutWp + WoutT -------
__global__ __launch_bounds__(256) void k_front(
    const float* __restrict__ value, const float* __restrict__ Wv,
    const float* __restrict__ bv, float* __restrict__ valp,
    const float* __restrict__ query, float* __restrict__ qcat,
    const float* __restrict__ Wo, const float* __restrict__ Wa,
    const float* __restrict__ bo, const float* __restrict__ ba,
    const float* __restrict__ camk, float* __restrict__ uv,
    float* __restrict__ out_keep,
    const float* __restrict__ Wout, const float* __restrict__ Wp,
    float* __restrict__ WoutWp, unsigned short* __restrict__ WoutT,
    int bs, int MV, int MQ, int nValp, int nQ, int nGeomBlk) {
  int blk = blockIdx.x;
  int tid = threadIdx.x;
  if (blk < nValp) {
    gemm_body<false>(value, Wv, bv, nullptr, nullptr, nullptr, nullptr,
                     valp, MV, kC, kC, blk & 3, blk >> 2);
  } else if (blk < nValp + nQ) {
    int r = blk - nValp;
    gemm_body<true>(query, nullptr, nullptr, Wo, Wa, bo, ba,
                    qcat, MQ, 128, kC, r & 1, r >> 1);
  } else if (blk < nValp + nQ + nGeomBlk) {
    int t = (blk - nValp - nQ) * 256 + tid;
    if (t >= bs * kLQ) return;
    int b = t / kLQ;
    int ij = t - b * kLQ;
    int i = ij / kNH;
    int j = ij - i * kNH;
    const float* K = camk + b * 9;
    float g0 = (float)(-25.6 + (double)j * (51.2 / 63.0));  //  y
    float g2 = (float)(25.6 - (double)i * 0.8);             // -x
    bool any = false;
    float* dst = uv + (size_t)t * 16;
    for (int k = 0; k < kNV; ++k) {
      float g1 = (float)(4.0 - (double)k * (8.0 / 7.0));    // -z
      float p0 = K[0] * g0 + K[1] * g1 + K[2] * g2;
      float p1 = K[3] * g0 + K[4] * g1 + K[5] * g2;
      float p2 = K[6] * g0 + K[7] * g1 + K[8] * g2;
      float den = (fabsf(p2) < 1e-6f) ? 1e-6f : p2;
      float u = p0 / den / 1408.0f;
      float v = p1 / den / 416.0f;
      any = any || (u >= 0.f && u <= 1.f && v >= 0.f && v <= 1.f);
      dst[k * 2]     = u;
      dst[k * 2 + 1] = v;
    }
    out_keep[t] = any ? 1.f : 0.f;
  } else if (blk < nValp + nQ + nGeomBlk + 64) {
    int r = (blk - nValp - nQ - nGeomBlk) * 4 + (tid >> 6);
    int lane = tid & 63;
    const float* row = Wout + (size_t)r * kC;
    float s = 0.f;
#pragma unroll
    for (int j = lane; j < kC; j += 64) s += row[j] * Wp[j];
#pragma unroll
    for (int o = 32; o > 0; o >>= 1) s += __shfl_down(s, o, 64);
    if (lane == 0) WoutWp[r] = s;
  } else {
    int c = blk - nValp - nQ - nGeomBlk - 64;   // column of Wout
    WoutT[(size_t)c * kC + tid] = f2bf(Wout[(size_t)tid * kC + c]);
  }
}

// ---------------- bf16 MFMA GEMM: out = Abf@Wout + bias + 2*query ------------------------
__global__ __launch_bounds__(256) void gemm_mfma(
    const unsigned short* __restrict__ Abf, const unsigned short* __restrict__ BT,
    const float* __restrict__ bias, const float* __restrict__ query,
    float* __restrict__ out, int M) {
  int gw = blockIdx.x * 4 + (threadIdx.x >> 6);
  int lane = threadIdx.x & 63;
  int tr = gw >> 4;                 // M/16 row tiles
  int tc = gw & 15;                 // 256/16 col tiles
  int r0 = tr * 16, c0 = tc * 16;
  if (r0 >= M) return;
  int lrow = lane & 15;
  int kgrp = lane >> 4;
  const unsigned short* Ap = Abf + (size_t)(r0 + lrow) * kC + kgrp * 8;
  const unsigned short* Bp = BT  + (size_t)(c0 + lrow) * kC + kgrp * 8;
  floatx4 acc = {0.f, 0.f, 0.f, 0.f};
#pragma unroll
  for (int k0 = 0; k0 < kC; k0 += 32) {
    short8 a = *reinterpret_cast<const short8*>(Ap + k0);
    short8 b = *reinterpret_cast<const short8*>(Bp + k0);
    acc = __builtin_amdgcn_mfma_f32_16x16x32_bf16(a, b, acc, 0, 0, 0);
  }
  int col = c0 + lrow;
  float bi = bias[col];
#pragma unroll
  for (int r = 0; r < 4; ++r) {
    int row = r0 + kgrp * 4 + r;
    out[(size_t)row * kC + col] =
        acc[r] + bi + 2.0f * query[(size_t)row * kC + col];
  }
}

// ---------------- fused sampling: 4 waves per (b,q), 2 views per wave --------------------
// lane l: head h = l>>3, channels h*32 + (l&7)*4 .. +3 (float4)
__global__ __launch_bounds__(256) void k_fused(
    const float* __restrict__ valp, const float* __restrict__ uv,
    const float* __restrict__ qcat, const float* __restrict__ WoutWp,
    unsigned short* __restrict__ msda_bf, float* __restrict__ out_mhi) {
  int bq = blockIdx.x;
  int b = bq / kLQ;
  int tid = threadIdx.x;
  int wp = tid >> 6;        // wave w handles views 2w, 2w+1
  int lane = tid & 63;
  int h = lane >> 3;
  int dq = lane & 7;
  int ch = h * 32 + dq * 4;

  const float* qp = qcat + (size_t)bq * 128;

  // attention softmax over P for this head
  float4 qa4 = *reinterpret_cast<const float4*>(qp + 64 + h * 4);
  float am = fmaxf(fmaxf(qa4.x, qa4.y), fmaxf(qa4.z, qa4.w));
  float e0 = expf(qa4.x - am), e1 = expf(qa4.y - am);
  float e2 = expf(qa4.z - am), e3 = expf(qa4.w - am);
  float ei = 1.f / (e0 + e1 + e2 + e3);
  float aw[4] = {e0 * ei, e1 * ei, e2 * ei, e3 * ei};

  float4 qo0 = *reinterpret_cast<const float4*>(qp + h * 8);
  float4 qo1 = *reinterpret_cast<const float4*>(qp + h * 8 + 4);
  float offx[4] = {qo0.x, qo0.z, qo1.x, qo1.z};
  float offy[4] = {qo0.y, qo0.w, qo1.y, qo1.w};

  // this wave's 2 view (u,v) pairs
  float4 t4 = reinterpret_cast<const float4*>(uv + (size_t)bq * 16)[wp];
  float ub[2], vb[2];
  ub[0] = t4.x * 88.0f - 0.5f;
  vb[0] = t4.y * 26.0f - 0.5f;
  ub[1] = t4.z * 88.0f - 0.5f;
  vb[1] = t4.w * 26.0f - 0.5f;

  const float* vp = valp + (size_t)b * (kHF * kWF) * kC + ch;
  float4 w4 = *reinterpret_cast<const float4*>(WoutWp + ch);

  __shared__ float lgs[kNV];
  __shared__ float wks[kNV];
  __shared__ float4 part[3][64];

  float4 sv[2];
#pragma unroll
  for (int vv = 0; vv < 2; ++vv) {
    float4 s4 = {0.f, 0.f, 0.f, 0.f};
#pragma unroll
    for (int p = 0; p < kP; ++p) {
      float px = ub[vv] + offx[p];
      float py = vb[vv] + offy[p];
      px = fminf(fmaxf(px, -10000.f), 10000.f);
      py = fminf(fmaxf(py, -10000.f), 10000.f);
      // all-4-corners-invalid iff sample outside (-1,88)x(-1,26): skip loads,
      // contribution is exactly 0 -> bit-identical
      if (px >= -1.f && px < 88.f && py >= -1.f && py < 26.f) {
        float x0f = floorf(px), y0f = floorf(py);
        float lx = px - x0f, ly = py - y0f;
        int x0 = (int)x0f, y0 = (int)y0f;
#pragma unroll
        for (int cy = 0; cy < 2; ++cy) {
#pragma unroll
          for (int cx = 0; cx < 2; ++cx) {
            int xi = x0 + cx, yi = y0 + cy;
            float w = (cx ? lx : 1.f - lx) * (cy ? ly : 1.f - ly) * aw[p];
            bool valid = (xi >= 0) && (xi < kWF) && (yi >= 0) && (yi < kHF);
            int xc = xi < 0 ? 0 : (xi > kWF - 1 ? kWF - 1 : xi);
            int yc = yi < 0 ? 0 : (yi > kHF - 1 ? kHF - 1 : yi);
            float4 g = *reinterpret_cast<const float4*>(vp + (yc * kWF + xc) * kC);
            float wv = valid ? w : 0.f;
            s4.x += wv * g.x; s4.y += wv * g.y; s4.z += wv * g.z; s4.w += wv * g.w;
          }
        }
      }
    }
    sv[vv] = s4;
    float lv = s4.x * w4.x + s4.y * w4.y + s4.z * w4.z + s4.w * w4.w;
#pragma unroll
    for (int o = 32; o > 0; o >>= 1) lv += __shfl_down(lv, o, 64);
    if (lane == 0) lgs[wp * 2 + vv] = lv;
  }
  __syncthreads();
  if (tid == 0) {
    // height softmax + argmax (v-independent constant terms cancel exactly)
    float m = -1e30f; int ai = 0;
#pragma unroll
    for (int v = 0; v < kNV; ++v)
      if (lgs[v] > m) { m = lgs[v]; ai = v; }
    float ssum = 0.f;
    float ev[kNV];
#pragma unroll
    for (int v = 0; v < kNV; ++v) { ev[v] = expf(lgs[v] - m); ssum += ev[v]; }
    float invs = 1.f / ssum;
#pragma unroll
    for (int v = 0; v < kNV; ++v) wks[v] = ev[v] * invs;
    out_mhi[bq] = (float)ai;
  }
  __syncthreads();
  float4 acc = {0.f, 0.f, 0.f, 0.f};
#pragma unroll
  for (int vv = 0; vv < 2; ++vv) {
    float wv = wks[wp * 2 + vv];
    acc.x += wv * sv[vv].x; acc.y += wv * sv[vv].y;
    acc.z += wv * sv[vv].z; acc.w += wv * sv[vv].w;
  }
  if (wp > 0) part[wp - 1][lane] = acc;
  __syncthreads();
  if (wp == 0) {
#pragma unroll
    for (int i = 0; i < 3; ++i) {
      float4 pp = part[i][lane];
      acc.x += pp.x; acc.y += pp.y; acc.z += pp.z; acc.w += pp.w;
    }
    ushort4 pk;
    pk.x = f2bf(acc.x); pk.y = f2bf(acc.y);
    pk.z = f2bf(acc.z); pk.w = f2bf(acc.w);
    *reinterpret_cast<ushort4*>(msda_bf + (size_t)bq * kC + ch) = pk;
  }
}

extern "C" void kernel_launch(void* const* d_in, const int* in_sizes, int n_in,
                              void* d_out, int out_size, void* d_ws, size_t ws_size,
                              hipStream_t stream) {
  if (n_in < 13) return;
  const float* query = (const float*)d_in[0];
  const float* value = (const float*)d_in[1];
  const float* camk  = (const float*)d_in[2];
  const float* Wv    = (const float*)d_in[3];
  const float* bv    = (const float*)d_in[4];
  const float* Wo    = (const float*)d_in[5];
  const float* bo    = (const float*)d_in[6];
  const float* Wa    = (const float*)d_in[7];
  const float* ba    = (const float*)d_in[8];
  const float* Wout  = (const float*)d_in[9];
  const float* bout  = (const float*)d_in[10];
  const float* Wp    = (const float*)d_in[11];
  int bs = in_sizes[0] / (kLQ * kC);
  int MQ = bs * kLQ;          // 4224
  int MV = bs * kHF * kWF;    // 4576

  float* ws = (float*)d_ws;
  size_t o = 0;
  float* valp    = ws + o; o += (size_t)MV * kC;
  float* uv      = ws + o; o += (size_t)MQ * 16;
  float* qcat    = ws + o; o += (size_t)MQ * 128;
  unsigned short* msda_bf = (unsigned short*)(ws + o); o += (size_t)MQ * kC / 2;
  float* WoutWp  = ws + o; o += kC;
  unsigned short* WoutT = (unsigned short*)(ws + o); o += (size_t)kC * kC / 2;
  (void)ws_size; (void)out_size;

  float* outp = (float*)d_out;
  float* out_grd  = outp;                          // bs*LQ*C
  float* out_mhi  = outp + (size_t)MQ * kC;        // bs*LQ
  float* out_keep = out_mhi + (size_t)MQ;          // bs*LQ

  int nGeomBlk = (MQ + 255) / 256;
  int yb0 = (MV + 31) / 32;
  int yb1 = (MQ + 31) / 32;
  int nValp = 4 * yb0;
  int nQ = 2 * yb1;
  k_front<<<nValp + nQ + nGeomBlk + 64 + 256, 256, 0, stream>>>(
      value, Wv, bv, valp, query, qcat, Wo, Wa, bo, ba,
      camk, uv, out_keep, Wout, Wp, WoutWp, WoutT,
      bs, MV, MQ, nValp, nQ, nGeomBlk);
  k_fused<<<MQ, 256, 0, stream>>>(valp, uv, qcat, WoutWp, msda_bf, out_mhi);
  gemm_mfma<<<MQ / 4, 256, 0, stream>>>(msda_bf, WoutT, bout, query, out_grd, MQ);
}